// Round 15
// baseline (53.654 us; speedup 1.0000x reference)
//
#include <hip/hip_runtime.h>

#define B_SZ   256
#define T_SZ   512
#define EMB    128
#define HID    256
#define NCLS   32000
#define NBLK   250
#define NPROD  32        // producer blocks (8 m-rows each = 256)
#define CNT_OFF 131072   // grid-barrier counter offset in d_ws

typedef __attribute__((ext_vector_type(8))) short short8;
typedef __attribute__((ext_vector_type(4))) float f32x4;

__device__ inline unsigned short bf16rne(float f) {
    union { float f; unsigned int u; } v; v.f = f;
    unsigned int u = v.u;
    u += 0x7FFFu + ((u >> 16) & 1u);
    return (unsigned short)(u >> 16);
}
__device__ inline unsigned pkhi(float lo, float hi) {
    union { float f; unsigned u; } a, b;
    a.f = lo; b.f = hi;
    return ((b.u + 0x8000u) & 0xFFFF0000u) | ((a.u + 0x8000u) >> 16);
}

// ---------------------------------------------------------------------------
// Single-dispatch fused kernel. 250 blocks x 512 thr, 132 KB static LDS ->
// 1 block/CU -> all co-resident (R8-R10 proven; occupancy 23.8%).
//
// All three prior fused failure modes fixed:
//  - SPILL (R8-R10: 1.6KB/thr scratch = the 207MB excess WRITE; quantified
//    by R12): no pinned register arrays anywhere; phase-B acc split into
//    two halves of 8 -> peak ~70 VGPR, safe even at the compiler's 128 cap.
//  - U-REDUNDANCY (98MB of the 125MB FETCH): only NPROD=32 producer blocks
//    run phase A (8 rows each, E transposed in LDS, e-broadcast reads),
//    U traffic = 32 x 393KB = 12.6 MB.
//  - SPIN STORM (R8->R10 720->387us): relaxed-atomic spin + s_sleep,
//    single release/acquire fences (R10's fix, kept verbatim).
//
// Timeline/CU: W stream (128KB gload_lds, waves 4-7) ~5-6us; phase A
// (waves 0-3 of producers) ~3us hidden under it; handshake ~0.2; phase B:
// W LDS->reg cvt, h broadcast gload_lds (frag-major, linear,
// conflict-free), 128 MFMA in 2 halves, f32x4 stores ~6us.
// ---------------------------------------------------------------------------
__global__ __launch_bounds__(512, 2)
void fused_lstm_logits(const int* __restrict__ X, const float* __restrict__ C_table,
                       const float* __restrict__ U_i, const float* __restrict__ b_i,
                       const float* __restrict__ U_c, const float* __restrict__ b_c,
                       const float* __restrict__ U_o, const float* __restrict__ b_o,
                       const float* __restrict__ Ww, const float* __restrict__ b_out,
                       unsigned short* __restrict__ hws, unsigned int* __restrict__ cnt,
                       float* __restrict__ out) {
    __shared__ float Wlds[32768];            // 128 KB W f32, reused as h bf16
    __shared__ float eT[EMB][8];             // 4 KB transposed E (producers)
    unsigned short* Hs = (unsigned short*)Wlds;

    const int t    = threadIdx.x;
    const int bid  = blockIdx.x;
    const int wid  = t >> 6;
    const int lane = t & 63;
    const int l15  = lane & 15;
    const int lq   = lane >> 4;
    const int nbase = bid * 128 + wid * 16;

    if (t >= 256) {
        // ---- waves 4-7: W stream (interleave eT staging after 8 rows) ----
        const int w4 = wid - 4;              // 0..3
        #pragma unroll
        for (int i = 0; i < 8; ++i) {
            const int r = w4 * 32 + i;
            const float* src = Ww + (size_t)(bid * 128 + r) * HID
                                  + ((lane ^ (r & 7)) << 2);
            __builtin_amdgcn_global_load_lds(
                (const __attribute__((address_space(1))) unsigned int*)src,
                (__attribute__((address_space(3))) unsigned int*)(Wlds + r * HID),
                16, 0, 0);
        }
        if (bid < NPROD) {
            const int tt  = t - 256, r = tt >> 5, c4 = tt & 31;
            const int tok = X[(size_t)(bid * 8 + r) * T_SZ + (T_SZ - 1)];
            const float4 ev = *reinterpret_cast<const float4*>(
                C_table + (size_t)tok * EMB + c4 * 4);
            eT[c4 * 4 + 0][r] = ev.x; eT[c4 * 4 + 1][r] = ev.y;
            eT[c4 * 4 + 2][r] = ev.z; eT[c4 * 4 + 3][r] = ev.w;
            asm volatile("s_waitcnt lgkmcnt(0)" ::: "memory");
        }
        #pragma unroll
        for (int i = 8; i < 32; ++i) {
            const int r = w4 * 32 + i;
            const float* src = Ww + (size_t)(bid * 128 + r) * HID
                                  + ((lane ^ (r & 7)) << 2);
            __builtin_amdgcn_global_load_lds(
                (const __attribute__((address_space(1))) unsigned int*)src,
                (__attribute__((address_space(3))) unsigned int*)(Wlds + r * HID),
                16, 0, 0);
        }
    }
    __builtin_amdgcn_s_barrier();            // B0: eT ready (W still in flight)
    __builtin_amdgcn_sched_barrier(0);

    if (t < 256) {
        if (bid < NPROD) {
            // ---- phase A: 8 m-rows, plain loop, NO pinned arrays ----
            const int k = t;
            float ai[8] = {}, ac[8] = {}, ao[8] = {};
            for (int ee = 0; ee < EMB; ++ee) {
                const f32x4 e0 = *reinterpret_cast<const f32x4*>(&eT[ee][0]);
                const f32x4 e1 = *reinterpret_cast<const f32x4*>(&eT[ee][4]);
                const float ui = U_i[ee * HID + k];
                const float uc = U_c[ee * HID + k];
                const float uo = U_o[ee * HID + k];
                #pragma unroll
                for (int r = 0; r < 4; ++r) {
                    ai[r]     += e0[r] * ui; ac[r]     += e0[r] * uc; ao[r]     += e0[r] * uo;
                    ai[4 + r] += e1[r] * ui; ac[4 + r] += e1[r] * uc; ao[4 + r] += e1[r] * uo;
                }
            }
            const float bi = b_i[k], bc = b_c[k], bo = b_o[k];
            #pragma unroll
            for (int r = 0; r < 8; ++r) {
                const int m = bid * 8 + r;
                const float i0 = 1.f / (1.f + expf(-(ai[r] + bi)));
                const float g0 = tanhf(ac[r] + bc);
                const float o0 = 1.f / (1.f + expf(-(ao[r] + bo)));
                const unsigned short hv = bf16rne(o0 * tanhf(i0 * g0));
                const int frag = (m >> 4) * 8 + (k >> 5);
                const int li   = ((k >> 3) & 3) * 16 + (m & 15);
                hws[frag * 512 + li * 8 + (k & 7)] = hv;
            }
            asm volatile("s_waitcnt vmcnt(0)" ::: "memory");   // h stores retired
        }
    } else {
        asm volatile("s_waitcnt vmcnt(0)" ::: "memory");       // W fully in LDS
    }
    __builtin_amdgcn_s_barrier();            // B_mid: block's h + W-LDS done
    __builtin_amdgcn_sched_barrier(0);

    // ---- grid handshake: relaxed spin (R10-proven), producers add ----
    if (t == 0) {
        __threadfence();                                        // release
        if (bid < NPROD)
            __hip_atomic_fetch_add(cnt, 1u, __ATOMIC_RELAXED,
                                   __HIP_MEMORY_SCOPE_AGENT);
        long g = 0;
        while (__hip_atomic_load(cnt, __ATOMIC_RELAXED,
                                 __HIP_MEMORY_SCOPE_AGENT) < (unsigned)NPROD
               && ++g < (1L << 16))
            __builtin_amdgcn_s_sleep(2);
        __threadfence();                                        // acquire
    }
    __builtin_amdgcn_s_barrier();            // B1: all h visible
    __builtin_amdgcn_sched_barrier(0);

    // ---- phase B: W stripe LDS -> regs, cvt bf16 (R9-verbatim swizzle) ----
    short8 aw[8];
    {
        const int R  = wid * 16 + l15;
        const int sw = R & 7;
        const float* rp = Wlds + R * HID;
        #pragma unroll
        for (int ks = 0; ks < 8; ++ks) {
            const int j0 = ks * 8 + lq * 2;
            f32x4 w0 = *reinterpret_cast<const f32x4*>(rp + ((j0 ^ sw) << 2));
            f32x4 w1 = *reinterpret_cast<const f32x4*>(rp + (((j0 + 1) ^ sw) << 2));
            union { short8 s; unsigned u[4]; } p;
            p.u[0] = pkhi(w0[0], w0[1]);
            p.u[1] = pkhi(w0[2], w0[3]);
            p.u[2] = pkhi(w1[0], w1[1]);
            p.u[3] = pkhi(w1[2], w1[3]);
            aw[ks] = p.s;
        }
    }
    asm volatile("s_waitcnt lgkmcnt(0)" ::: "memory");
    __builtin_amdgcn_s_barrier();            // B2: W reads done, LDS reusable
    __builtin_amdgcn_sched_barrier(0);

    // ---- stage h (frag-major, linear, conflict-free) into LDS ----
    #pragma unroll
    for (int j = 0; j < 16; ++j) {
        const unsigned short* src = hws + (wid * 16 + j) * 512 + lane * 8;
        __builtin_amdgcn_global_load_lds(
            (const __attribute__((address_space(1))) unsigned int*)src,
            (__attribute__((address_space(3))) unsigned int*)(Hs + (wid * 16 + j) * 512),
            16, 0, 0);
    }
    asm volatile("s_waitcnt vmcnt(0)" ::: "memory");
    __builtin_amdgcn_s_barrier();            // B3: h in LDS
    __builtin_amdgcn_sched_barrier(0);

    // ---- MFMA in 2 halves of 8 mf (acc[8]=32 VGPR -> no spill) ----
    const unsigned short* hbase = Hs + lane * 8;
    const f32x4 bv = *reinterpret_cast<const f32x4*>(b_out + nbase + lq * 4);
    #pragma unroll
    for (int half = 0; half < 2; ++half) {
        f32x4 acc[8] = {};
        #pragma unroll
        for (int ks = 0; ks < 8; ++ks)
            #pragma unroll
            for (int mf8 = 0; mf8 < 8; ++mf8) {
                const int mf = half * 8 + mf8;
                short8 bh = *reinterpret_cast<const short8*>(
                    hbase + (mf * 8 + ks) * 512);
                acc[mf8] = __builtin_amdgcn_mfma_f32_16x16x32_bf16(
                    aw[ks], bh, acc[mf8], 0, 0, 0);
            }
        #pragma unroll
        for (int mf8 = 0; mf8 < 8; ++mf8) {
            const int mf = half * 8 + mf8;
            f32x4 o = acc[mf8] + bv;
            *reinterpret_cast<f32x4*>(
                out + (size_t)(mf * 16 + l15) * NCLS + nbase + lq * 4) = o;
        }
    }
}

// ---------------------------------------------------------------------------
extern "C" void kernel_launch(void* const* d_in, const int* in_sizes, int n_in,
                              void* d_out, int out_size, void* d_ws, size_t ws_size,
                              hipStream_t stream) {
    const int*   X       = (const int*)  d_in[0];
    const float* C_table = (const float*)d_in[1];
    const float* U_i     = (const float*)d_in[2];
    const float* b_i     = (const float*)d_in[4];
    const float* U_c     = (const float*)d_in[8];
    const float* b_c     = (const float*)d_in[10];
    const float* U_o     = (const float*)d_in[11];
    const float* b_o     = (const float*)d_in[13];
    const float* W_w     = (const float*)d_in[26];
    const float* b_out   = (const float*)d_in[27];
    float* out = (float*)d_out;

    unsigned short* hws = (unsigned short*)d_ws;                   // 128 KB
    unsigned int*   cnt = (unsigned int*)((char*)d_ws + CNT_OFF);

    hipMemsetAsync(cnt, 0, 4, stream);   // zero handshake counter each call

    fused_lstm_logits<<<NBLK, 512, 0, stream>>>(
        X, C_table, U_i, b_i, U_c, b_c, U_o, b_o, W_w, b_out, hws, cnt, out);
}

// Round 16
// 28.057 us; speedup vs baseline: 1.9123x; 1.9123x over previous
//
#include <hip/hip_runtime.h>

#define B_SZ   256
#define T_SZ   512
#define EMB    128
#define HID    256
#define NCLS   32000

typedef __attribute__((ext_vector_type(8))) short short8;
typedef __attribute__((ext_vector_type(4))) float f32x4;

__device__ inline unsigned short bf16rne(float f) {
    union { float f; unsigned int u; } v; v.f = f;
    unsigned int u = v.u;
    u += 0x7FFFu + ((u >> 16) & 1u);
    return (unsigned short)(u >> 16);
}
__device__ inline unsigned pkhi(float lo, float hi) {
    union { float f; unsigned u; } a, b;
    a.f = lo; b.f = hi;
    return ((b.u + 0x8000u) & 0xFFFF0000u) | ((a.u + 0x8000u) >> 16);
}

// ---------------------------------------------------------------------------
// h is stored FRAG-MAJOR in d_ws: element (m,k) at
//   frag = (m>>4)*8 + (k>>5); lane = ((k>>3)&3)*16 + (m&15);
//   idx  = frag*512 + lane*8 + (k&7)
// Each B-fragment is a contiguous lane-linear 1 KB block: LDS staging in
// logits is linear (no swizzle, rule 21), ds_read_b128 conflict-free.
// ---------------------------------------------------------------------------

// ---------------------------------------------------------------------------
// Kernel 1 (R16 change): h_last for t = T-1 only (layer-0 state never
// updates; layer-1 scan discarded).
// R14 diagnosis: 20 GB/s/CU == 16 waves x 1 outstanding load / 450cy L3
// latency -> per-wave load serialization. Fix: inner loop in 4 chunks of
// 8 ee with a PINNED 24-load batch (ui/uc/uo x8) issued before the FMAs.
// 24 in flight/wave x 16 waves saturates; ~45 VGPR (R12's spill came from
// pinning 144 regs at 1 wave/CU - not this).
// ---------------------------------------------------------------------------
__global__ __launch_bounds__(1024)
void lstm_h_last(const int* __restrict__ X, const float* __restrict__ C_table,
                 const float* __restrict__ U_i, const float* __restrict__ b_i,
                 const float* __restrict__ U_c, const float* __restrict__ b_c,
                 const float* __restrict__ U_o, const float* __restrict__ b_o,
                 unsigned short* __restrict__ hws) {
    __shared__ float e[EMB];
    __shared__ float part[3][4][HID];    // 12 KB
    const int m = blockIdx.x;
    const int t = threadIdx.x;           // 0..1023
    const int k = t & 255;               // hidden index
    const int q = t >> 8;                // ee-quarter 0..3

    const int token = X[(size_t)m * T_SZ + (T_SZ - 1)];   // uniform -> s_load
    if (t < EMB) e[t] = C_table[(size_t)token * EMB + t];
    __syncthreads();

    float ai = 0.f, ac = 0.f, ao = 0.f;
    const int ee0q = q * 32;
    #pragma unroll
    for (int c = 0; c < 4; ++c) {        // 4 chunks of 8 ee
        const int ee0 = ee0q + c * 8;
        float ui[8], uc[8], uo[8];
        #pragma unroll
        for (int j = 0; j < 8; ++j) {
            const int ee = ee0 + j;
            ui[j] = U_i[ee * HID + k];
            uc[j] = U_c[ee * HID + k];
            uo[j] = U_o[ee * HID + k];
        }
        #pragma unroll
        for (int j = 0; j < 8; ++j)
            asm volatile("" : "+v"(ui[j]), "+v"(uc[j]), "+v"(uo[j]));
        #pragma unroll
        for (int j = 0; j < 8; ++j) {
            const float ev = e[ee0 + j];              // LDS broadcast
            ai += ev * ui[j]; ac += ev * uc[j]; ao += ev * uo[j];
        }
    }
    part[0][q][k] = ai;
    part[1][q][k] = ac;
    part[2][q][k] = ao;
    __syncthreads();

    if (q == 0) {
        const float si = part[0][0][k] + part[0][1][k] + part[0][2][k] + part[0][3][k];
        const float sc = part[1][0][k] + part[1][1][k] + part[1][2][k] + part[1][3][k];
        const float so = part[2][0][k] + part[2][1][k] + part[2][2][k] + part[2][3][k];
        const float i0 = 1.f / (1.f + expf(-(si + b_i[k])));
        const float g0 = tanhf(sc + b_c[k]);
        const float o0 = 1.f / (1.f + expf(-(so + b_o[k])));
        const unsigned short hv = bf16rne(o0 * tanhf(i0 * g0));
        const int frag = (m >> 4) * 8 + (k >> 5);
        const int li   = ((k >> 3) & 3) * 16 + (m & 15);
        hws[frag * 512 + li * 8 + (k & 7)] = hv;
    }
}

// ---------------------------------------------------------------------------
// Kernel 2: logits[m][n] = sum_k h[m][k]*W[n][k] + b_out[n].  M=256 N=32000
// K=256.  VERBATIM R7 (~9us incl. gap via R12/R14 decomposition): one-shot,
// one barrier, W direct to regs (16 fully-coalesced dwordx4 per wave = its
// own 16-row n-stripe), h staged linearly to LDS via global_load_lds
// (frag-major, conflict-free), 128 MFMA, acc[16], stores at end.
// ---------------------------------------------------------------------------
__global__ __launch_bounds__(512, 2)
void logits_gemm(const unsigned short* __restrict__ hws,
                 const float* __restrict__ Ww,
                 const float* __restrict__ b_out,
                 float* __restrict__ out) {
    __shared__ unsigned short Hs[B_SZ * HID];   // 128 KB, frag-major linear

    const int t    = threadIdx.x;        // 0..511
    const int wid  = t >> 6;             // 0..7
    const int lane = t & 63;
    const int l15  = lane & 15;
    const int lq   = lane >> 4;          // 0..3

    const int nbase = blockIdx.x * 128 + wid * 16;

    // ---- 1. W loads: full K=256 stripe for this lane's n-row ----
    const float* wrow = Ww + (size_t)(nbase + l15) * HID + lq * 8;
    f32x4 wf[16];
    #pragma unroll
    for (int ks = 0; ks < 8; ++ks) {
        wf[2 * ks]     = *reinterpret_cast<const f32x4*>(wrow + ks * 32);
        wf[2 * ks + 1] = *reinterpret_cast<const f32x4*>(wrow + ks * 32 + 4);
    }

    // ---- 2. stage h slice [wid*16KB, +16KB): 16 x 1KB, fully linear ----
    #pragma unroll
    for (int j = 0; j < 16; ++j) {
        const unsigned short* src = hws + (wid * 16 + j) * 512;
        __builtin_amdgcn_global_load_lds(
            (const __attribute__((address_space(1))) unsigned int*)(src + lane * 8),
            (__attribute__((address_space(3))) unsigned int*)(Hs + (wid * 16 + j) * 512),
            16, 0, 0);
    }

    // ---- 3. pin W (forces materialization), drain, barrier ----
    #pragma unroll
    for (int i = 0; i < 16; ++i) asm volatile("" : "+v"(wf[i]));
    asm volatile("s_waitcnt vmcnt(0)" ::: "memory");
    __builtin_amdgcn_s_barrier();
    __builtin_amdgcn_sched_barrier(0);

    // ---- 4. convert W to bf16 A-fragments ----
    short8 aw[8];
    #pragma unroll
    for (int ks = 0; ks < 8; ++ks) {
        union { short8 s; unsigned u[4]; } p;
        p.u[0] = pkhi(wf[2 * ks][0],     wf[2 * ks][1]);
        p.u[1] = pkhi(wf[2 * ks][2],     wf[2 * ks][3]);
        p.u[2] = pkhi(wf[2 * ks + 1][0], wf[2 * ks + 1][1]);
        p.u[3] = pkhi(wf[2 * ks + 1][2], wf[2 * ks + 1][3]);
        aw[ks] = p.s;
    }

    f32x4 bv = *reinterpret_cast<const f32x4*>(b_out + nbase + lq * 4);

    // ---- MFMA: ks-outer -> 16 independent acc chains ----
    const unsigned short* hbase = Hs + lane * 8;
    f32x4 acc[16] = {};
    #pragma unroll
    for (int ks = 0; ks < 8; ++ks) {
        #pragma unroll
        for (int mf = 0; mf < 16; ++mf) {
            short8 bh = *reinterpret_cast<const short8*>(
                hbase + (mf * 8 + ks) * 512);
            acc[mf] = __builtin_amdgcn_mfma_f32_16x16x32_bf16(
                aw[ks], bh, acc[mf], 0, 0, 0);
        }
    }

    // ---- 5. epilogue: bias + stores ----
    #pragma unroll
    for (int mf = 0; mf < 16; ++mf) {
        f32x4 o = acc[mf] + bv;
        *reinterpret_cast<f32x4*>(
            out + (size_t)(mf * 16 + l15) * NCLS + nbase + lq * 4) = o;
    }
}

// ---------------------------------------------------------------------------
extern "C" void kernel_launch(void* const* d_in, const int* in_sizes, int n_in,
                              void* d_out, int out_size, void* d_ws, size_t ws_size,
                              hipStream_t stream) {
    const int*   X       = (const int*)  d_in[0];
    const float* C_table = (const float*)d_in[1];
    const float* U_i     = (const float*)d_in[2];
    const float* b_i     = (const float*)d_in[4];
    const float* U_c     = (const float*)d_in[8];
    const float* b_c     = (const float*)d_in[10];
    const float* U_o     = (const float*)d_in[11];
    const float* b_o     = (const float*)d_in[13];
    const float* W_w     = (const float*)d_in[26];
    const float* b_out   = (const float*)d_in[27];
    float* out = (float*)d_out;

    unsigned short* hws = (unsigned short*)d_ws;  // bf16 h_last, frag-major

    lstm_h_last<<<B_SZ, 1024, 0, stream>>>(X, C_table, U_i, b_i, U_c, b_c,
                                           U_o, b_o, hws);
    logits_gemm<<<NCLS / 128, 512, 0, stream>>>(hws, W_w, b_out, out);
}